// Round 14
// baseline (32.279 us; speedup 1.0000x reference)
//
#include <hip/hip_runtime.h>
#include <math.h>

#define L_SEQ 4096   // sequence length L
#define NT 1024      // threads per block (one block per sequence)
#define CHUNK 4      // elements per thread
#define NW (NT/64)   // waves per block (16)

typedef float f2 __attribute__((ext_vector_type(2)));

__device__ __forceinline__ f2 mkf2(float a, float b) { f2 r; r.x = a; r.y = b; return r; }
__device__ __forceinline__ f2 max2(f2 a, f2 b) { return mkf2(fmaxf(a.x, b.x), fmaxf(a.y, b.y)); }
__device__ __forceinline__ float hmax(f2 v) { return fmaxf(v.x, v.y); }

struct M2 { f2 r0, r1; };   // rows: r0=(a00,a01), r1=(a10,a11)

// max-plus 2x2 compose: C[s][t] = max_k(A[s][k] + B[k][t])  (packed rows)
__device__ __forceinline__ M2 mpc(const M2& A, const M2& B) {
  M2 C;
  C.r0 = max2(mkf2(A.r0.x, A.r0.x) + B.r0, mkf2(A.r0.y, A.r0.y) + B.r1);
  C.r1 = max2(mkf2(A.r1.x, A.r1.x) + B.r0, mkf2(A.r1.y, A.r1.y) + B.r1);
  return C;
}
// row-vector max-plus apply: r[t] = max_s(v[s] + M[s][t])
__device__ __forceinline__ f2 mapply(f2 v, const M2& M) {
  return max2(mkf2(v.x, v.x) + M.r0, mkf2(v.y, v.y) + M.r1);
}
__device__ __forceinline__ f2 colmax(const M2& M) { return max2(M.r0, M.r1); }

__device__ __forceinline__ M2 ld4(float4 v) { M2 M; M.r0 = mkf2(v.x, v.y); M.r1 = mkf2(v.z, v.w); return M; }
__device__ __forceinline__ float4 st4(const M2& M) { return make_float4(M.r0.x, M.r0.y, M.r1.x, M.r1.y); }

// DPP cross-lane fetch (VALU pipe). 0x110+N = row_shr:N, 0x142 = row_bcast:15,
// 0x143 = row_bcast:31, 0x138 = wave_shr:1.
template <int CTRL>
__device__ __forceinline__ float dppf(float x) {
  return __int_as_float(__builtin_amdgcn_update_dpp(
      0, __float_as_int(x), CTRL, 0xf, 0xf, true));
}
template <int CTRL>
__device__ __forceinline__ f2 dpp2(f2 x) { return mkf2(dppf<CTRL>(x.x), dppf<CTRL>(x.y)); }
template <int CTRL>
__device__ __forceinline__ M2 dpp_fetch(const M2& x) {
  M2 r; r.r0 = dpp2<CTRL>(x.r0); r.r1 = dpp2<CTRL>(x.r1); return r;
}
__device__ __forceinline__ float rdl(float x, int l) {
  return __int_as_float(__builtin_amdgcn_readlane(__float_as_int(x), l));
}

__global__ __launch_bounds__(NT, 8) void chain_fb_kernel(
    const float* __restrict__ jp, const float* __restrict__ bp,
    const int* __restrict__ obs, float* __restrict__ out) {
  __shared__ f2 T4r0[16], T4r1[16];   // 4-bit-pattern LUT rows (256 B)
  __shared__ float4 wtf[NW];          // fwd wave totals
  __shared__ float4 wtbr[NW];         // bwd wave totals, REVERSED slot order

  const int t = threadIdx.x;
  const int lane = t & 63;
  const int w = t >> 6;
  const long b = blockIdx.x;

  const float P   = 0.25f * jp[0];   // psi = [[P,-P],[-P,P]]
  const float hb0 = 0.5f * bp[0];    // u_i = 0.5*b[obs_i]; phi_i = (-u, +u)
  const float hb1 = 0.5f * bp[1];

  // ---- issue obs load first (16B/thread, coalesced)
  const int4 q0 = *(const int4*)(obs + b * L_SEQ + (long)t * CHUNK);

  // ---- build T4 LUT: pattern p -> E(p0)(*)E(p1)(*)E(p2)(*)E(p3)
  //      (bit 0 = earliest element);  E(u): r0=(P-u, -u-P), r1=(u-P, u+P)
  if (t < 16) {
    float u0 = (t & 1) ? hb1 : hb0;
    M2 Tt; Tt.r0 = mkf2(P - u0, -u0 - P); Tt.r1 = mkf2(u0 - P, u0 + P);
    #pragma unroll
    for (int k = 1; k < 4; ++k) {
      float uk = ((t >> k) & 1) ? hb1 : hb0;
      M2 Ek; Ek.r0 = mkf2(P - uk, -uk - P); Ek.r1 = mkf2(uk - P, uk + P);
      Tt = mpc(Tt, Ek);
    }
    T4r0[t] = Tt.r0; T4r1[t] = Tt.r1;
  }
  // pack 4-bit obs mask while the barrier drains
  const unsigned m =
      (unsigned)(q0.x & 1)      | (unsigned)(q0.y & 1) << 1 |
      (unsigned)(q0.z & 1) << 2 | (unsigned)(q0.w & 1) << 3;
  __syncthreads();

  // ---- chunk transforms: fwd for own chunk; bwd for MIRRORED chunk (v-space)
  const unsigned mrev = (unsigned)__shfl((int)m, 63 - lane);
  const unsigned r = __brev(mrev) >> 28;   // 4-bit reversal: bwd element order
  M2 T;  T.r0  = T4r0[m]; T.r1  = T4r1[m];   // fwd: E(u0)(*)...(*)E(u3)
  M2 Rv; Rv.r0 = T4r0[r]; Rv.r1 = T4r1[r];   // bwd of chunk 63-lane

  // ---- dual Hillis-Steele inclusive scans via DPP (VALU pipe)
  {
    M2 f, g;
    f = dpp_fetch<0x111>(T); g = dpp_fetch<0x111>(Rv);           // row_shr:1
    if ((lane & 15) >= 1) { T = mpc(f, T); Rv = mpc(g, Rv); }
    f = dpp_fetch<0x112>(T); g = dpp_fetch<0x112>(Rv);           // row_shr:2
    if ((lane & 15) >= 2) { T = mpc(f, T); Rv = mpc(g, Rv); }
    f = dpp_fetch<0x114>(T); g = dpp_fetch<0x114>(Rv);           // row_shr:4
    if ((lane & 15) >= 4) { T = mpc(f, T); Rv = mpc(g, Rv); }
    f = dpp_fetch<0x118>(T); g = dpp_fetch<0x118>(Rv);           // row_shr:8
    if ((lane & 15) >= 8) { T = mpc(f, T); Rv = mpc(g, Rv); }
    f = dpp_fetch<0x142>(T); g = dpp_fetch<0x142>(Rv);           // row_bcast:15
    if (lane & 16)        { T = mpc(f, T); Rv = mpc(g, Rv); }
    f = dpp_fetch<0x143>(T); g = dpp_fetch<0x143>(Rv);           // row_bcast:31
    if (lane >= 32)       { T = mpc(f, T); Rv = mpc(g, Rv); }
  }
  if (lane == 63) { wtf[w] = st4(T); wtbr[NW - 1 - w] = st4(Rv); }

  __syncthreads();  // wave totals visible

  // ---- cross-wave tail: 16-lane DPP mini-scan of wave totals (each 16-lane
  //      row scans an identical copy; lanes 0-14 read via readlane).
  M2 Xf = ld4(wtf[lane & 15]);
  M2 Xb = ld4(wtbr[lane & 15]);
  {
    M2 f, g;
    f = dpp_fetch<0x111>(Xf); g = dpp_fetch<0x111>(Xb);
    if ((lane & 15) >= 1) { Xf = mpc(f, Xf); Xb = mpc(g, Xb); }
    f = dpp_fetch<0x112>(Xf); g = dpp_fetch<0x112>(Xb);
    if ((lane & 15) >= 2) { Xf = mpc(f, Xf); Xb = mpc(g, Xb); }
    f = dpp_fetch<0x114>(Xf); g = dpp_fetch<0x114>(Xb);
    if ((lane & 15) >= 4) { Xf = mpc(f, Xf); Xb = mpc(g, Xb); }
    f = dpp_fetch<0x118>(Xf); g = dpp_fetch<0x118>(Xb);
    if ((lane & 15) >= 8) { Xf = mpc(f, Xf); Xb = mpc(g, Xb); }
  }
  const f2 Vf = colmax(Xf);   // lane l: msg after waves 0..l
  const f2 Vb = colmax(Xb);   // lane l: msg after waves 15..15-l (bwd)

  f2 v, vb;   // wave-incoming messages (wave-uniform)
  if (w > 0)      v  = mkf2(rdl(Vf.x, w - 1), rdl(Vf.y, w - 1));
  else            v  = mkf2(0.f, 0.f);
  if (w < NW - 1) vb = mkf2(rdl(Vb.x, NW - 2 - w), rdl(Vb.y, NW - 2 - w));
  else            vb = mkf2(0.f, 0.f);

  // per-lane exclusive messages: apply v through own inclusive scan, shift
  // down one lane (wave_shr:1); lane 0 = wave-incoming.
  f2 wv  = mapply(v,  T);
  f2 wvb = mapply(vb, Rv);
  f2 fm  = dpp2<0x138>(wv);
  f2 bmv = dpp2<0x138>(wvb);
  if (lane == 0) { fm = v; bmv = vb; }
  // bwd message computed at v-lane (63-lane): mirror back
  f2 bm = mkf2(__shfl(bmv.x, 63 - lane), __shfl(bmv.y, 63 - lane));

  // ---- hoisted per-element phi vectors: uv[e] = (-u_e, +u_e)
  f2 uv[CHUNK];
  #pragma unroll
  for (int e = 0; e < CHUNK; ++e) {
    float u = ((m >> e) & 1) ? hb1 : hb0;
    uv[e] = mkf2(-u, u);
  }

  const f2 pp = mkf2(P, -P), pm = mkf2(-P, P);

  // ---- fwd replay: o = phi + fwd  (xy is exactly phi+msg)
  f2 o[CHUNK];
  #pragma unroll
  for (int e = 0; e < CHUNK; ++e) {
    f2 xy = fm + uv[e];
    o[e] = xy;
    fm = mkf2(hmax(xy + pp), hmax(xy + pm));
  }
  // ---- bwd replay: add bwd message (right->left)
  #pragma unroll
  for (int e = CHUNK - 1; e >= 0; --e) {
    o[e] += bm;
    f2 xy = bm + uv[e];
    bm = mkf2(hmax(xy + pp), hmax(xy + pm));
  }

  // ---- store: contiguous 4 floats per state row (coalesced float4s)
  const long base = (long)t * CHUNK;
  float* r0 = out + b * (2L * L_SEQ) + base;   // out[b][0][base..]
  float* r1 = r0 + L_SEQ;                      // out[b][1][base..]
  *(float4*)r0 = make_float4(o[0].x, o[1].x, o[2].x, o[3].x);
  *(float4*)r1 = make_float4(o[0].y, o[1].y, o[2].y, o[3].y);
}

extern "C" void kernel_launch(void* const* d_in, const int* in_sizes, int n_in,
                              void* d_out, int out_size, void* d_ws, size_t ws_size,
                              hipStream_t stream) {
  const float* jp  = (const float*)d_in[0];
  const float* bp  = (const float*)d_in[1];
  const int*   obs = (const int*)d_in[2];
  float* out = (float*)d_out;
  const int B = in_sizes[2] / L_SEQ;   // 2048
  chain_fb_kernel<<<B, NT, 0, stream>>>(jp, bp, obs, out);
}